// Round 7
// baseline (101.474 us; speedup 1.0000x reference)
//
#include <hip/hip_runtime.h>

typedef _Float16 f16x8 __attribute__((ext_vector_type(8)));
typedef _Float16 f16x4 __attribute__((ext_vector_type(4)));
typedef __fp16 fp16x2 __attribute__((ext_vector_type(2)));
typedef float f32x4 __attribute__((ext_vector_type(4)));

#define IMG 512
#define NB 32
#define OUTC 118
#define OUTR 32
#define GX 5
#define GY 16
#define NBLK (GX*GY*NB)
#define INSTR 48           /* lds_in slot stride (fp16): 96B, 16B-aligned rows */
#define VSTR 136           /* lds_v col stride (fp16): 272B, 16B-aligned rows */
#define VOFF (16*VSTR)

// sigma=1.5, 11-tap normalized Gaussian (validated R1-R6, absmax 0.0)
#define GW_LIST { 0.0010283804f, 0.0075987583f, 0.0360007700f, 0.1093606900f, \
  0.2130055300f, 0.2660117200f, 0.2130055300f, 0.1093606900f, 0.0360007700f, \
  0.0075987583f, 0.0010283804f }

__global__ __launch_bounds__(256, 3) void ssim_mfma(const float* __restrict__ img1,
                                                    const float* __restrict__ img2,
                                                    unsigned long long* __restrict__ wsum,
                                                    unsigned int* __restrict__ wticket,
                                                    float* __restrict__ out) {
    // input, col-major per column (K=rows contiguous), fp16; slots 42..47 zero
    __shared__ _Float16 lds_in[2][128][INSTR];
    // v-conv output V[row][col], row-major fp16 (+pad cols 128..135 zeroed, +tail)
    __shared__ _Float16 lds_v[5*VOFF + 32];
    __shared__ _Float16 gwt[64];
    __shared__ float red[4];

    const int tid  = threadIdx.x;
    const int lane = tid & 63;
    const int lm   = lane & 15;
    const int kg   = lane >> 4;
    const int w    = tid >> 6;

    const int bx = blockIdx.x, by = blockIdx.y, bz = blockIdx.z;
    const float* __restrict__ p1 = img1 + (size_t)bz * (IMG*IMG);
    const float* __restrict__ p2 = img2 + (size_t)bz * (IMG*IMG);
    const int x0 = bx * OUTC;
    const int y0 = by * OUTR;

    // staging ids: 128 cols x 2 slot-halves (24 slots each)
    const int ci = tid & 127;
    const int hh = tid >> 7;
    const int gc = x0 - 5 + ci;
    const bool okc = (gc >= 0) && (gc < IMG);
    const int gcc  = okc ? gc : 0;

    // ---- single-pass staging: 42 real rows (y0-5 .. y0+36), slots 42..47 zero ----
    {
        union { fp16x2 p2v[12]; f16x8 v[3]; } ua, ub;
        const int slot0 = hh * 24;
#pragma unroll
        for (int pp = 0; pp < 12; ++pp) {
            const int s0 = slot0 + 2*pp;
            const int ar0 = y0 - 5 + s0;
            const int ar1 = ar0 + 1;
            const bool ok0 = okc & (s0   < 42) & (ar0 >= 0) & (ar0 < IMG);
            const bool ok1 = okc & (s0+1 < 42) & (ar1 >= 0) & (ar1 < IMG);
            const int i0 = ok0 ? ar0 : 0, i1 = ok1 ? ar1 : 0;
            float a0 = p1[i0*IMG + gcc], a1 = p1[i1*IMG + gcc];
            float b0 = p2[i0*IMG + gcc], b1 = p2[i1*IMG + gcc];
            a0 = ok0 ? a0 : 0.f;  a1 = ok1 ? a1 : 0.f;
            b0 = ok0 ? b0 : 0.f;  b1 = ok1 ? b1 : 0.f;
            ua.p2v[pp] = __builtin_amdgcn_cvt_pkrtz(a0, a1);
            ub.p2v[pp] = __builtin_amdgcn_cvt_pkrtz(b0, b1);
        }
#pragma unroll
        for (int m = 0; m < 3; ++m) {
            *(f16x8*)&lds_in[0][ci][slot0 + 8*m] = ua.v[m];
            *(f16x8*)&lds_in[1][ci][slot0 + 8*m] = ub.v[m];
        }
    }
    // ---- gaussian table + lds_v pad zeroing (keeps stray reads finite) ----
    {
        const float GWc[11] = GW_LIST;
        if (tid < 64) {
            float wv = 0.f;
            const int t = tid - 16;
#pragma unroll
            for (int k = 0; k < 11; ++k) if (t == k) wv = GWc[k];
            gwt[tid] = (_Float16)wv;
        }
        f16x8 z = {};
        if (tid >= 64 && tid < 144) {          // 80 pad rows: cols 128..135
            const int u = tid - 64;
            const int f = u / 16, r = u % 16;
            *(f16x8*)&lds_v[f*VOFF + r*VSTR + 128] = z;
        } else if (tid >= 144 && tid < 148) {  // 32-elem tail
            *(f16x8*)&lds_v[5*VOFF + (tid-144)*8] = z;
        }
    }
    __syncthreads();

    // banded weight fragment: serves as B[k][n]=GW[k-n] for BOTH conv stages
    union { _Float16 h[8]; f16x8 v; } wu;
#pragma unroll
    for (int i = 0; i < 8; ++i) wu.h[i] = gwt[16 + kg*8 + i - lm];

    float local = 0.f;
    const f32x4 zc = {0.f, 0.f, 0.f, 0.f};

    // stage V: A = X^T (data, b128 from col-major lds_in), B = weights.
    // D[m=col][n=out_row]: lane holds out_row=lm, cols kg*4+j  -> one b64 per field
    auto stage_v = [&](int sbase) {
#pragma unroll
        for (int q = 0; q < 2; ++q) {
            const int cb = 2*w + q;
            const f16x8 xf = *(const f16x8*)&lds_in[0][cb*16 + lm][sbase + kg*8];
            const f16x8 yf = *(const f16x8*)&lds_in[1][cb*16 + lm][sbase + kg*8];
            const f16x8 fr0 = xf, fr1 = yf;
            const f16x8 fr2 = xf*xf, fr3 = yf*yf, fr4 = xf*yf;
            const int cbase = cb*16 + kg*4;
#define DO_F(F, FR) { \
            const f32x4 d = __builtin_amdgcn_mfma_f32_16x16x32_f16(FR, wu.v, zc, 0, 0, 0); \
            union { fp16x2 p[2]; f16x4 v4; } pk; \
            pk.p[0] = __builtin_amdgcn_cvt_pkrtz(d[0], d[1]); \
            pk.p[1] = __builtin_amdgcn_cvt_pkrtz(d[2], d[3]); \
            *(f16x4*)&lds_v[(F)*VOFF + lm*VSTR + cbase] = pk.v4; }
            DO_F(0, fr0) DO_F(1, fr1) DO_F(2, fr2) DO_F(3, fr3) DO_F(4, fr4)
#undef DO_F
        }
    };

    // stage H: A = V rows (b128, k=cols contiguous), B = weights; + SSIM map
    auto stage_h = [&]() {
#pragma unroll
        for (int q = 0; q < 2; ++q) {
            const int xx = 2*w + q;
            const int cb2 = xx*16 + kg*8;
            const f16x8 a0 = *(const f16x8*)&lds_v[0*VOFF + lm*VSTR + cb2];
            const f16x8 a1 = *(const f16x8*)&lds_v[1*VOFF + lm*VSTR + cb2];
            const f16x8 a2 = *(const f16x8*)&lds_v[2*VOFF + lm*VSTR + cb2];
            const f16x8 a3 = *(const f16x8*)&lds_v[3*VOFF + lm*VSTR + cb2];
            const f16x8 a4 = *(const f16x8*)&lds_v[4*VOFF + lm*VSTR + cb2];
            const f32x4 d0 = __builtin_amdgcn_mfma_f32_16x16x32_f16(a0, wu.v, zc, 0,0,0);
            const f32x4 d1 = __builtin_amdgcn_mfma_f32_16x16x32_f16(a1, wu.v, zc, 0,0,0);
            const f32x4 d2 = __builtin_amdgcn_mfma_f32_16x16x32_f16(a2, wu.v, zc, 0,0,0);
            const f32x4 d3 = __builtin_amdgcn_mfma_f32_16x16x32_f16(a3, wu.v, zc, 0,0,0);
            const f32x4 d4 = __builtin_amdgcn_mfma_f32_16x16x32_f16(a4, wu.v, zc, 0,0,0);
            const int X = xx*16 + lm;
            const bool valid = (X < OUTC) & (x0 + X < IMG);
            float s4 = 0.f;
#pragma unroll
            for (int j = 0; j < 4; ++j) {
                const float mu1 = d0[j], mu2 = d1[j];
                const float m11 = mu1*mu1, m22 = mu2*mu2, m12 = mu1*mu2;
                const float s1 = d2[j] - m11, s2 = d3[j] - m22, sx = d4[j] - m12;
                const float num = (2.f*m12 + 1e-4f) * (2.f*sx + 9e-4f);
                const float den = (m11 + m22 + 1e-4f) * (s1 + s2 + 9e-4f);
                s4 += num * __builtin_amdgcn_rcpf(den);
            }
            local += valid ? s4 : 0.f;
        }
    };

    // ================= strip 0 (out rows y0..y0+15) =================
    stage_v(0);
    __syncthreads();
    stage_h();
    __syncthreads();
    // ================= strip 1 (out rows y0+16..y0+31) ==============
    stage_v(16);
    __syncthreads();
    stage_h();

    // ---- block reduction + deterministic fixed-point global accumulate ----
#pragma unroll
    for (int off = 32; off > 0; off >>= 1)
        local += __shfl_down(local, off, 64);
    if (lane == 0) red[w] = local;
    __syncthreads();
    if (tid == 0) {
        const float s = red[0] + red[1] + red[2] + red[3];
        // quantize to 2^-31 fixed point: bitwise-deterministic sum, error ~1e-9/block
        const long long q = (long long)rint((double)s * 2147483648.0);
        atomicAdd(wsum, (unsigned long long)q);
        __threadfence();
        const unsigned int t = atomicAdd(wticket, 1u);
        if (t == (unsigned int)(NBLK - 1)) {
            __threadfence();
            const unsigned long long tot = atomicAdd(wsum, 0ULL);
            const double mean = (double)(long long)tot / 2147483648.0 / 8388608.0;
            out[0] = (float)(1.0 - mean);
        }
    }
}

extern "C" void kernel_launch(void* const* d_in, const int* in_sizes, int n_in,
                              void* d_out, int out_size, void* d_ws, size_t ws_size,
                              hipStream_t stream) {
    const float* img1 = (const float*)d_in[0];
    const float* img2 = (const float*)d_in[1];
    float* out = (float*)d_out;
    unsigned long long* wsum = (unsigned long long*)d_ws;
    unsigned int* wticket = (unsigned int*)((char*)d_ws + 8);

    hipMemsetAsync(d_ws, 0, 16, stream);   // zero sum + ticket (graph-capturable)
    dim3 grid(GX, GY, NB);                 // 5 x 16 x 32 = 2560 blocks
    ssim_mfma<<<grid, 256, 0, stream>>>(img1, img2, wsum, wticket, out);
}

// Round 8
// 28.422 us; speedup vs baseline: 3.5702x; 3.5702x over previous
//
#include <hip/hip_runtime.h>

typedef _Float16 f16x8 __attribute__((ext_vector_type(8)));
typedef _Float16 f16x4 __attribute__((ext_vector_type(4)));
typedef __fp16 fp16x2 __attribute__((ext_vector_type(2)));
typedef float f32x4 __attribute__((ext_vector_type(4)));

#define IMG 512
#define NB 32
#define OUTC 118
#define OUTR 32
#define GX 5
#define GY 16
#define NBLK (GX*GY*NB)    /* 2560 */
#define INSTR 48           /* lds_in slot stride (fp16): 96B, 16B-aligned rows */
#define VSTR 136           /* lds_v col stride (fp16): 272B, 16B-aligned rows */
#define VOFF (16*VSTR)

// sigma=1.5, 11-tap normalized Gaussian (validated R1-R7, absmax 0.0)
#define GW_LIST { 0.0010283804f, 0.0075987583f, 0.0360007700f, 0.1093606900f, \
  0.2130055300f, 0.2660117200f, 0.2130055300f, 0.1093606900f, 0.0360007700f, \
  0.0075987583f, 0.0010283804f }

__global__ __launch_bounds__(256, 3) void ssim_mfma(const float* __restrict__ img1,
                                                    const float* __restrict__ img2,
                                                    float* __restrict__ partials) {
    // input, col-major per column (K=rows contiguous), fp16; slots 42..47 zero
    __shared__ _Float16 lds_in[2][128][INSTR];
    // v-conv output V[row][col], row-major fp16 (+pad cols 128..135 zeroed, +tail)
    __shared__ _Float16 lds_v[5*VOFF + 32];
    __shared__ _Float16 gwt[64];
    __shared__ float red[4];

    const int tid  = threadIdx.x;
    const int lane = tid & 63;
    const int lm   = lane & 15;
    const int kg   = lane >> 4;
    const int w    = tid >> 6;

    const int bx = blockIdx.x, by = blockIdx.y, bz = blockIdx.z;
    const float* __restrict__ p1 = img1 + (size_t)bz * (IMG*IMG);
    const float* __restrict__ p2 = img2 + (size_t)bz * (IMG*IMG);
    const int x0 = bx * OUTC;
    const int y0 = by * OUTR;

    // staging ids: 128 cols x 2 slot-halves (24 slots each)
    const int ci = tid & 127;
    const int hh = tid >> 7;
    const int gc = x0 - 5 + ci;
    const bool okc = (gc >= 0) && (gc < IMG);
    const int gcc  = okc ? gc : 0;

    // ---- single-pass staging: 42 real rows (y0-5 .. y0+36), slots 42..47 zero ----
    {
        union { fp16x2 p2v[12]; f16x8 v[3]; } ua, ub;
        const int slot0 = hh * 24;
#pragma unroll
        for (int pp = 0; pp < 12; ++pp) {
            const int s0 = slot0 + 2*pp;
            const int ar0 = y0 - 5 + s0;
            const int ar1 = ar0 + 1;
            const bool ok0 = okc & (s0   < 42) & (ar0 >= 0) & (ar0 < IMG);
            const bool ok1 = okc & (s0+1 < 42) & (ar1 >= 0) & (ar1 < IMG);
            const int i0 = ok0 ? ar0 : 0, i1 = ok1 ? ar1 : 0;
            float a0 = p1[i0*IMG + gcc], a1 = p1[i1*IMG + gcc];
            float b0 = p2[i0*IMG + gcc], b1 = p2[i1*IMG + gcc];
            a0 = ok0 ? a0 : 0.f;  a1 = ok1 ? a1 : 0.f;
            b0 = ok0 ? b0 : 0.f;  b1 = ok1 ? b1 : 0.f;
            ua.p2v[pp] = __builtin_amdgcn_cvt_pkrtz(a0, a1);
            ub.p2v[pp] = __builtin_amdgcn_cvt_pkrtz(b0, b1);
        }
#pragma unroll
        for (int m = 0; m < 3; ++m) {
            *(f16x8*)&lds_in[0][ci][slot0 + 8*m] = ua.v[m];
            *(f16x8*)&lds_in[1][ci][slot0 + 8*m] = ub.v[m];
        }
    }
    // ---- gaussian table + lds_v pad zeroing (keeps stray reads finite) ----
    {
        const float GWc[11] = GW_LIST;
        if (tid < 64) {
            float wv = 0.f;
            const int t = tid - 16;
#pragma unroll
            for (int k = 0; k < 11; ++k) if (t == k) wv = GWc[k];
            gwt[tid] = (_Float16)wv;
        }
        f16x8 z = {};
        if (tid >= 64 && tid < 144) {          // 80 pad rows: cols 128..135
            const int u = tid - 64;
            const int f = u / 16, r = u % 16;
            *(f16x8*)&lds_v[f*VOFF + r*VSTR + 128] = z;
        } else if (tid >= 144 && tid < 148) {  // 32-elem tail
            *(f16x8*)&lds_v[5*VOFF + (tid-144)*8] = z;
        }
    }
    __syncthreads();

    // banded weight fragment: serves as B[k][n]=GW[k-n] for BOTH conv stages
    union { _Float16 h[8]; f16x8 v; } wu;
#pragma unroll
    for (int i = 0; i < 8; ++i) wu.h[i] = gwt[16 + kg*8 + i - lm];

    float local = 0.f;
    const f32x4 zc = {0.f, 0.f, 0.f, 0.f};

    // stage V: A = X^T (data, b128 from col-major lds_in), B = weights.
    // D[m=col][n=out_row]: lane holds out_row=lm, cols kg*4+j  -> one b64 per field
    auto stage_v = [&](int sbase) {
#pragma unroll
        for (int q = 0; q < 2; ++q) {
            const int cb = 2*w + q;
            const f16x8 xf = *(const f16x8*)&lds_in[0][cb*16 + lm][sbase + kg*8];
            const f16x8 yf = *(const f16x8*)&lds_in[1][cb*16 + lm][sbase + kg*8];
            const f16x8 fr0 = xf, fr1 = yf;
            const f16x8 fr2 = xf*xf, fr3 = yf*yf, fr4 = xf*yf;
            const int cbase = cb*16 + kg*4;
#define DO_F(F, FR) { \
            const f32x4 d = __builtin_amdgcn_mfma_f32_16x16x32_f16(FR, wu.v, zc, 0, 0, 0); \
            union { fp16x2 p[2]; f16x4 v4; } pk; \
            pk.p[0] = __builtin_amdgcn_cvt_pkrtz(d[0], d[1]); \
            pk.p[1] = __builtin_amdgcn_cvt_pkrtz(d[2], d[3]); \
            *(f16x4*)&lds_v[(F)*VOFF + lm*VSTR + cbase] = pk.v4; }
            DO_F(0, fr0) DO_F(1, fr1) DO_F(2, fr2) DO_F(3, fr3) DO_F(4, fr4)
#undef DO_F
        }
    };

    // stage H: A = V rows (b128, k=cols contiguous), B = weights; + SSIM map
    auto stage_h = [&]() {
#pragma unroll
        for (int q = 0; q < 2; ++q) {
            const int xx = 2*w + q;
            const int cb2 = xx*16 + kg*8;
            const f16x8 a0 = *(const f16x8*)&lds_v[0*VOFF + lm*VSTR + cb2];
            const f16x8 a1 = *(const f16x8*)&lds_v[1*VOFF + lm*VSTR + cb2];
            const f16x8 a2 = *(const f16x8*)&lds_v[2*VOFF + lm*VSTR + cb2];
            const f16x8 a3 = *(const f16x8*)&lds_v[3*VOFF + lm*VSTR + cb2];
            const f16x8 a4 = *(const f16x8*)&lds_v[4*VOFF + lm*VSTR + cb2];
            const f32x4 d0 = __builtin_amdgcn_mfma_f32_16x16x32_f16(a0, wu.v, zc, 0,0,0);
            const f32x4 d1 = __builtin_amdgcn_mfma_f32_16x16x32_f16(a1, wu.v, zc, 0,0,0);
            const f32x4 d2 = __builtin_amdgcn_mfma_f32_16x16x32_f16(a2, wu.v, zc, 0,0,0);
            const f32x4 d3 = __builtin_amdgcn_mfma_f32_16x16x32_f16(a3, wu.v, zc, 0,0,0);
            const f32x4 d4 = __builtin_amdgcn_mfma_f32_16x16x32_f16(a4, wu.v, zc, 0,0,0);
            const int X = xx*16 + lm;
            const bool valid = (X < OUTC) & (x0 + X < IMG);
            float s4 = 0.f;
#pragma unroll
            for (int j = 0; j < 4; ++j) {
                const float mu1 = d0[j], mu2 = d1[j];
                const float m11 = mu1*mu1, m22 = mu2*mu2, m12 = mu1*mu2;
                const float s1 = d2[j] - m11, s2 = d3[j] - m22, sx = d4[j] - m12;
                const float num = (2.f*m12 + 1e-4f) * (2.f*sx + 9e-4f);
                const float den = (m11 + m22 + 1e-4f) * (s1 + s2 + 9e-4f);
                s4 += num * __builtin_amdgcn_rcpf(den);
            }
            local += valid ? s4 : 0.f;
        }
    };

    // ================= strip 0 (out rows y0..y0+15) =================
    stage_v(0);
    __syncthreads();
    stage_h();
    __syncthreads();
    // ================= strip 1 (out rows y0+16..y0+31) ==============
    stage_v(16);
    __syncthreads();
    stage_h();

    // ---- block reduction ----
#pragma unroll
    for (int off = 32; off > 0; off >>= 1)
        local += __shfl_down(local, off, 64);
    if (lane == 0) red[w] = local;
    __syncthreads();
    if (tid == 0) {
        partials[(size_t)((bz*GY + by)*GX + bx)] = red[0] + red[1] + red[2] + red[3];
    }
}

__global__ __launch_bounds__(256) void ssim_finalize(const float* __restrict__ partials,
                                                     float* __restrict__ out) {
    __shared__ double red[4];
    double s = 0.0;
    // 2560 partials = 640 float4
    for (int i = threadIdx.x; i < NBLK/4; i += 256) {
        const float4 v = reinterpret_cast<const float4*>(partials)[i];
        s += (double)v.x + (double)v.y + (double)v.z + (double)v.w;
    }
#pragma unroll
    for (int off = 32; off > 0; off >>= 1)
        s += __shfl_down(s, off, 64);
    if ((threadIdx.x & 63) == 0) red[threadIdx.x >> 6] = s;
    __syncthreads();
    if (threadIdx.x == 0) {
        double tot = red[0] + red[1] + red[2] + red[3];
        out[0] = (float)(1.0 - tot / (32.0 * 512.0 * 512.0));
    }
}

extern "C" void kernel_launch(void* const* d_in, const int* in_sizes, int n_in,
                              void* d_out, int out_size, void* d_ws, size_t ws_size,
                              hipStream_t stream) {
    const float* img1 = (const float*)d_in[0];
    const float* img2 = (const float*)d_in[1];
    float* out = (float*)d_out;
    float* partials = (float*)d_ws;

    dim3 grid(GX, GY, NB);   // 5 x 16 x 32 = 2560 blocks
    ssim_mfma<<<grid, 256, 0, stream>>>(img1, img2, partials);
    ssim_finalize<<<1, 256, 0, stream>>>(partials, out);
}